// Round 1
// baseline (216.106 us; speedup 1.0000x reference)
//
#include <hip/hip_runtime.h>

typedef __bf16 bf16x8 __attribute__((ext_vector_type(8)));
typedef float  floatx4 __attribute__((ext_vector_type(4)));

#define HW   56
#define NPIX 3136
#define CIN  128
#define COUT 256

// W2 layout: [cc(4)][tap(9)][oc(256)][ci(32)], bf16. 294912 elems = 576 KB of d_ws.
__global__ __launch_bounds__(256) void wt_transform_kernel(
        const float* __restrict__ Kw, __bf16* __restrict__ W2) {
    int idx = blockIdx.x * 256 + threadIdx.x;     // 0 .. 294911, coalesced write
    int ci    = idx & 31;
    int oc    = (idx >> 5) & 255;
    int tapcc = idx >> 13;                        // cc*9 + tap
    int tap   = tapcc % 9;
    int cc    = tapcc / 9;
    int c = cc * 32 + ci;
    int r = tap / 3, s = tap % 3;
    W2[idx] = (__bf16)Kw[oc * 1152 + c * 9 + r * 3 + s];
}

// Block: 256 thr = 4 waves. Tile: 128 oc x (2 rows x 64 wcols; 56 valid).
// K-loop: 4 c-chunks x 9 taps, MFMA f32_16x16x32_bf16.
// Wave w: oc quarter = wid*32 (2 m-tiles), all 128 positions (8 n-tiles).
__global__ __launch_bounds__(256) void conv_kernel(
        const float* __restrict__ x, const __bf16* __restrict__ W2,
        const float* __restrict__ bias, float* __restrict__ out) {
    __shared__ __align__(16) __bf16 Xs[4][66][32];   // [inrow][wp=iw+1][c], 16.9 KB

    const int t    = threadIdx.x;
    const int n    = blockIdx.x / 28;
    const int ht   = blockIdx.x % 28;
    const int h0   = ht * 2;
    const int ocb  = blockIdx.y * 128;

    const int wid  = t >> 6;
    const int lane = t & 63;
    const int quad = lane >> 4;
    const int l15  = lane & 15;

    floatx4 acc[2][8];
    #pragma unroll
    for (int mi = 0; mi < 2; ++mi)
        #pragma unroll
        for (int nj = 0; nj < 8; ++nj)
            acc[mi][nj] = (floatx4){0.f, 0.f, 0.f, 0.f};

    // Zero-fill halo columns wp==0 and wp in [57,66) once (staging never touches them).
    if (t < 160) {
        int pr = t >> 2;            // 0..39 = 4 rows x 10 wp
        int zr = pr / 10;
        int zw = pr % 10;
        int wp = (zw == 0) ? 0 : (56 + zw);   // 0, 57..65
        *(int4*)&Xs[zr][wp][(t & 3) * 8] = make_int4(0, 0, 0, 0);
    }

    // Staging map: thread -> (c, row, half-of-width); 7 float4 loads each.
    const int q    = t >> 1;        // 0..127
    const int half = t & 1;
    const int srow = q & 3;         // input row 0..3  (h0-1 .. h0+2)
    const int sc   = q >> 2;        // c within chunk 0..31
    const int hin  = h0 - 1 + srow;
    const bool hvalid = (unsigned)hin < 56u;

    for (int cc = 0; cc < 4; ++cc) {
        __syncthreads();            // protect Xs against overwrite
        const float* src = x + ((n * CIN + cc * 32 + sc) * NPIX) + hin * HW;
        #pragma unroll
        for (int j = 0; j < 7; ++j) {
            int w4 = (half * 7 + j) * 4;           // 0..52 step 4
            float4 v;
            if (hvalid) v = *(const float4*)(src + w4);   // 16B aligned
            else        v = make_float4(0.f, 0.f, 0.f, 0.f);
            Xs[srow][1 + w4 + 0][sc] = (__bf16)v.x;
            Xs[srow][1 + w4 + 1][sc] = (__bf16)v.y;
            Xs[srow][1 + w4 + 2][sc] = (__bf16)v.z;
            Xs[srow][1 + w4 + 3][sc] = (__bf16)v.w;
        }
        __syncthreads();

        #pragma unroll
        for (int tap = 0; tap < 9; ++tap) {
            const int r = tap / 3, s = tap % 3;
            // A-fragments: one dwordx4 per m-tile, straight from L2-resident W2.
            const bf16x8* wb = (const bf16x8*)(W2 + (size_t)(cc * 9 + tap) * (256 * 32));
            bf16x8 afr[2];
            #pragma unroll
            for (int mi = 0; mi < 2; ++mi) {
                int oc = ocb + wid * 32 + mi * 16 + l15;   // A[m=lane&15][k=quad*8+j]
                afr[mi] = wb[oc * 4 + quad];
            }
            // B-fragments: one ds_read_b128 per n-tile. B[n=lane&15][k=quad*8+j]
            bf16x8 bfr[8];
            #pragma unroll
            for (int nj = 0; nj < 8; ++nj) {
                int p  = nj * 16 + l15;     // position in 128-tile
                int pr = p >> 6;            // output row 0/1
                int pw = p & 63;            // padded col
                bfr[nj] = *(const bf16x8*)&Xs[pr + r][pw + s][quad * 8];
            }
            #pragma unroll
            for (int mi = 0; mi < 2; ++mi)
                #pragma unroll
                for (int nj = 0; nj < 8; ++nj)
                    acc[mi][nj] = __builtin_amdgcn_mfma_f32_16x16x32_bf16(
                        afr[mi], bfr[nj], acc[mi][nj], 0, 0, 0);
        }
    }

    // Epilogue: C/D layout col=lane&15 (pos), row=quad*4+reg (oc). Add scalar bias.
    const float bv = bias[0];
    #pragma unroll
    for (int nj = 0; nj < 8; ++nj) {
        int p  = nj * 16 + l15;
        int pr = p >> 6;
        int pw = p & 63;
        if (pw < 56) {
            int hout = h0 + pr;
            #pragma unroll
            for (int mi = 0; mi < 2; ++mi) {
                int oc = ocb + wid * 32 + mi * 16 + quad * 4;
                float* o = out + ((n * COUT + oc) * NPIX) + hout * HW + pw;
                o[0 * NPIX] = acc[mi][nj].x + bv;
                o[1 * NPIX] = acc[mi][nj].y + bv;
                o[2 * NPIX] = acc[mi][nj].z + bv;
                o[3 * NPIX] = acc[mi][nj].w + bv;
            }
        }
    }
}

extern "C" void kernel_launch(void* const* d_in, const int* in_sizes, int n_in,
                              void* d_out, int out_size, void* d_ws, size_t ws_size,
                              hipStream_t stream) {
    const float* x    = (const float*)d_in[0];
    const float* Kw   = (const float*)d_in[1];
    const float* bias = (const float*)d_in[2];
    float* out = (float*)d_out;
    __bf16* W2 = (__bf16*)d_ws;   // needs 589824 bytes of workspace

    wt_transform_kernel<<<dim3(1152), dim3(256), 0, stream>>>(Kw, W2);
    conv_kernel<<<dim3(32 * 28, 2), dim3(256), 0, stream>>>(x, W2, bias, out);
}

// Round 2
// 209.336 us; speedup vs baseline: 1.0323x; 1.0323x over previous
//
#include <hip/hip_runtime.h>

typedef __bf16 bf16x8 __attribute__((ext_vector_type(8)));
typedef float  floatx16 __attribute__((ext_vector_type(16)));

#define HW   56
#define NPIX 3136
#define CIN  128
#define COUT 256

// W2 layout: [cc(4)][tap(9)][cg(4)][oc(256)][j(8)], bf16. 294912 elems = 576 KB of d_ws.
// cg*8+j = ci within the 32-c chunk; A-fragment lanes read 16B chunks contiguous in oc.
__global__ __launch_bounds__(256) void wt_transform_kernel(
        const float* __restrict__ Kw, __bf16* __restrict__ W2) {
    int idx = blockIdx.x * 256 + threadIdx.x;     // coalesced write
    int j     = idx & 7;
    int oc    = (idx >> 3) & 255;
    int cg    = (idx >> 11) & 3;
    int tapcc = idx >> 13;                        // cc*9 + tap
    int tap   = tapcc % 9;
    int cc    = tapcc / 9;
    int c = cc * 32 + cg * 8 + j;
    W2[idx] = (__bf16)Kw[oc * 1152 + c * 9 + tap];
}

// Xs logical [row(6)][wp(66)][ci(32)] bf16, with 8-elem chunk XOR swizzle on cg.
__device__ __forceinline__ int xs_idx(int row, int wp, int cg) {
    return row * 2112 + wp * 32 + ((cg ^ ((wp >> 1) & 3)) << 3);
}

// Block: 256 thr = 4 waves. Block tile: 128 oc x 256 pos (4 out-rows x 64 wpad).
// Wave: 64 oc x 128 pos -> 2 m-tiles x 4 n-tiles of 32x32x16 MFMA, acc = 128 VGPR.
__global__ __launch_bounds__(256, 2) void conv_kernel(
        const float* __restrict__ x, const __bf16* __restrict__ W2,
        const float* __restrict__ bias, float* __restrict__ out) {
    __shared__ __align__(16) __bf16 Xs[6 * 66 * 32];   // 25.3 KB

    const int t    = threadIdx.x;
    const int nb   = blockIdx.x / 14;
    const int ht   = blockIdx.x % 14;
    const int h0   = ht * 4;
    const int ocb  = blockIdx.y * 128;

    const int wid  = t >> 6;
    const int lane = t & 63;
    const int half = lane >> 5;
    const int l31  = lane & 31;

    const int oc_base = ocb + (wid & 1) * 64;   // wave's 64-oc slice
    const int p_base  = (wid >> 1) * 128;       // wave's 128-position slice

    floatx16 acc[2][4];
    #pragma unroll
    for (int mi = 0; mi < 2; ++mi)
        #pragma unroll
        for (int nj = 0; nj < 4; ++nj)
            #pragma unroll
            for (int k = 0; k < 16; ++k)
                acc[mi][nj][k] = 0.f;

    // Zero halo columns wp==0 and wp in [57,66): 6 rows x 10 wp x 4 cg = 240 b128 chunks.
    if (t < 240) {
        int cg   = t & 3;
        int rest = t >> 2;            // 0..59
        int row  = rest / 10;
        int zw   = rest % 10;
        int wp   = (zw == 0) ? 0 : (56 + zw);
        *(int4*)&Xs[xs_idx(row, wp, cg)] = make_int4(0, 0, 0, 0);
    }

    // Staging map: thread -> (w = t&63, cgroup = t>>6), 6 rows each.
    const int  sw     = t & 63;
    const int  sg     = t >> 6;       // == wid, so cg uniform per wave -> conflict-free writes
    const bool wvalid = sw < 56;

    for (int cc = 0; cc < 4; ++cc) {
        __syncthreads();              // protect Xs against overwrite
        for (int row = 0; row < 6; ++row) {
            int hin = h0 - 1 + row;
            bf16x8 v;
            #pragma unroll
            for (int j = 0; j < 8; ++j) v[j] = (__bf16)0.f;
            if (wvalid && (unsigned)hin < 56u) {
                const float* src = x + (size_t)(nb * CIN + cc * 32 + sg * 8) * NPIX
                                     + hin * HW + sw;
                #pragma unroll
                for (int j = 0; j < 8; ++j)
                    v[j] = (__bf16)src[j * NPIX];   // coalesced across lanes (w-consecutive)
            }
            if (wvalid)
                *(bf16x8*)&Xs[xs_idx(row, 1 + sw, sg)] = v;   // one ds_write_b128
        }
        __syncthreads();

        #pragma unroll
        for (int tap = 0; tap < 9; ++tap) {
            const int r = tap / 3, s = tap % 3;
            const __bf16* wtap = W2 + (size_t)(cc * 9 + tap) * (4 * 256 * 8);
            #pragma unroll
            for (int kc = 0; kc < 2; ++kc) {
                // A-fragments: contiguous 16B/lane from L2-resident W2.
                bf16x8 afr[2];
                #pragma unroll
                for (int mi = 0; mi < 2; ++mi) {
                    int oc = oc_base + mi * 32 + l31;
                    afr[mi] = *(const bf16x8*)(wtap + ((kc * 2 + half) * 256 + oc) * 8);
                }
                #pragma unroll
                for (int nj = 0; nj < 4; ++nj) {
                    int p  = p_base + nj * 32 + l31;
                    int pr = p >> 6;              // out-row 0..3
                    int pw = p & 63;
                    bf16x8 bfr = *(const bf16x8*)&Xs[xs_idx(pr + r, pw + s, kc * 2 + half)];
                    #pragma unroll
                    for (int mi = 0; mi < 2; ++mi)
                        acc[mi][nj] = __builtin_amdgcn_mfma_f32_32x32x16_bf16(
                            afr[mi], bfr, acc[mi][nj], 0, 0, 0);
                }
            }
        }
    }

    // Epilogue: C/D 32x32 layout col=lane&31 (pos), row=(reg&3)+8*(reg>>2)+4*(lane>>5) (oc).
    const float bv = bias[0];
    #pragma unroll
    for (int nj = 0; nj < 4; ++nj) {
        int p  = p_base + nj * 32 + l31;
        int pr = p >> 6;
        int pw = p & 63;
        if (pw < 56) {
            int hout = h0 + pr;
            #pragma unroll
            for (int mi = 0; mi < 2; ++mi) {
                #pragma unroll
                for (int rg = 0; rg < 16; ++rg) {
                    int oc = oc_base + mi * 32 + (rg & 3) + ((rg >> 2) << 3) + half * 4;
                    out[(size_t)(nb * COUT + oc) * NPIX + hout * HW + pw] = acc[mi][nj][rg] + bv;
                }
            }
        }
    }
}

extern "C" void kernel_launch(void* const* d_in, const int* in_sizes, int n_in,
                              void* d_out, int out_size, void* d_ws, size_t ws_size,
                              hipStream_t stream) {
    const float* x    = (const float*)d_in[0];
    const float* Kw   = (const float*)d_in[1];
    const float* bias = (const float*)d_in[2];
    float* out = (float*)d_out;
    __bf16* W2 = (__bf16*)d_ws;   // needs 589824 bytes of workspace

    wt_transform_kernel<<<dim3(1152), dim3(256), 0, stream>>>(Kw, W2);
    conv_kernel<<<dim3(32 * 14, 2), dim3(256), 0, stream>>>(x, W2, bias, out);
}

// Round 3
// 207.657 us; speedup vs baseline: 1.0407x; 1.0081x over previous
//
#include <hip/hip_runtime.h>

typedef __bf16 bf16x8 __attribute__((ext_vector_type(8)));
typedef float  floatx16 __attribute__((ext_vector_type(16)));

#define HW   56
#define NPIX 3136
#define CIN  128
#define COUT 256

// W2 layout: [cc(4)][tap(9)][cg(4)][oc(256)][j(8)], bf16. 576 KB of d_ws.
__global__ __launch_bounds__(256) void wt_transform_kernel(
        const float* __restrict__ Kw, __bf16* __restrict__ W2) {
    int idx = blockIdx.x * 256 + threadIdx.x;     // coalesced write
    int j     = idx & 7;
    int oc    = (idx >> 3) & 255;
    int cg    = (idx >> 11) & 3;
    int tapcc = idx >> 13;                        // cc*9 + tap
    int tap   = tapcc % 9;
    int cc    = tapcc / 9;
    int c = cc * 32 + cg * 8 + j;
    W2[idx] = (__bf16)Kw[oc * 1152 + c * 9 + tap];
}

// Xs: [row(4)][wp(66)][slot(40)] bf16; slots 0..31 = ci (cg*8+j), 32..39 pad.
// Stride 40 elems = 80 B: bank-base advances 20 banks/wp -> 8 distinct 4-bank
// spans per 8 consecutive wp -> conflict-free b128 reads and writes.
__device__ __forceinline__ int xs_idx(int row, int wp, int cg) {
    return row * 2640 + wp * 40 + cg * 8;
}

// Block: 256 thr = 4 waves. Block tile: 128 oc x 128 pos (2 out-rows x 64 wpad).
// Wave: 64 oc x 64 pos (one out-row) -> 2mi x 2nj of 32x32x16, acc = 64 AGPR.
// 3 waves/SIMD target: latency hiding was the R2 bottleneck (all pipes <25%).
__global__ __launch_bounds__(256, 3) void conv_kernel(
        const float* __restrict__ x, const __bf16* __restrict__ W2,
        const float* __restrict__ bias, float* __restrict__ out) {
    __shared__ __align__(16) __bf16 Xs[4 * 2640];   // 21.1 KB

    const int t    = threadIdx.x;
    const int nb   = blockIdx.x / 28;
    const int ht   = blockIdx.x % 28;
    const int h0   = ht * 2;
    const int ocb  = blockIdx.y * 128;

    const int wid  = t >> 6;
    const int lane = t & 63;
    const int half = lane >> 5;
    const int l31  = lane & 31;

    const int oc_base = ocb + (wid & 1) * 64;   // wave's 64-oc slice
    const int prow    = wid >> 1;               // wave's output row (0/1)

    floatx16 acc[2][2];
    #pragma unroll
    for (int mi = 0; mi < 2; ++mi)
        #pragma unroll
        for (int nj = 0; nj < 2; ++nj)
            #pragma unroll
            for (int k = 0; k < 16; ++k)
                acc[mi][nj][k] = 0.f;

    // Zero halo columns wp==0 and wp in [57,66): 4 rows x 10 wp x 4 cg = 160.
    if (t < 160) {
        int cg   = t & 3;
        int rest = t >> 2;            // 0..39
        int row  = rest / 10;
        int zw   = rest % 10;
        int wp   = (zw == 0) ? 0 : (56 + zw);
        *(int4*)&Xs[xs_idx(row, wp, cg)] = make_int4(0, 0, 0, 0);
    }

    // Staging map: thread -> (w = t&63, cg = t>>6); 4 rows x 8 c-strided loads.
    const int  sw     = t & 63;
    const int  sg     = t >> 6;       // cg uniform per wave -> clean b128 writes
    const bool wvalid = sw < 56;

    for (int cc = 0; cc < 4; ++cc) {
        __syncthreads();              // protect Xs against overwrite
        #pragma unroll
        for (int row = 0; row < 4; ++row) {
            int hin = h0 - 1 + row;
            bf16x8 v;
            #pragma unroll
            for (int j = 0; j < 8; ++j) v[j] = (__bf16)0.f;
            if (wvalid && (unsigned)hin < 56u) {
                const float* src = x + (size_t)(nb * CIN + cc * 32 + sg * 8) * NPIX
                                     + hin * HW + sw;
                #pragma unroll
                for (int j = 0; j < 8; ++j)
                    v[j] = (__bf16)src[j * NPIX];   // coalesced across lanes
            }
            if (wvalid)
                *(bf16x8*)&Xs[xs_idx(row, 1 + sw, sg)] = v;   // one ds_write_b128
        }
        __syncthreads();

        #pragma unroll
        for (int tap = 0; tap < 9; ++tap) {
            const int r = tap / 3, s = tap % 3;
            const __bf16* wtap = W2 + (size_t)(cc * 9 + tap) * (4 * 256 * 8);
            #pragma unroll
            for (int kc = 0; kc < 2; ++kc) {
                // A-fragments: contiguous 16B/lane, W2 tap-slice is L1-resident.
                bf16x8 afr[2];
                #pragma unroll
                for (int mi = 0; mi < 2; ++mi) {
                    int oc = oc_base + mi * 32 + l31;
                    afr[mi] = *(const bf16x8*)(wtap + ((kc * 2 + half) * 256 + oc) * 8);
                }
                bf16x8 bfr[2];
                #pragma unroll
                for (int nj = 0; nj < 2; ++nj) {
                    int pw = nj * 32 + l31;
                    bfr[nj] = *(const bf16x8*)&Xs[xs_idx(prow + r, pw + s, kc * 2 + half)];
                }
                #pragma unroll
                for (int mi = 0; mi < 2; ++mi)
                    #pragma unroll
                    for (int nj = 0; nj < 2; ++nj)
                        acc[mi][nj] = __builtin_amdgcn_mfma_f32_32x32x16_bf16(
                            afr[mi], bfr[nj], acc[mi][nj], 0, 0, 0);
            }
        }
    }

    // Epilogue: C/D 32x32 layout col=lane&31 (pos), row=(rg&3)+8*(rg>>2)+4*half (oc).
    const float bv = bias[0];
    const int hout = h0 + prow;
    #pragma unroll
    for (int nj = 0; nj < 2; ++nj) {
        int pw = nj * 32 + l31;
        if (pw < 56) {
            #pragma unroll
            for (int mi = 0; mi < 2; ++mi) {
                #pragma unroll
                for (int rg = 0; rg < 16; ++rg) {
                    int oc = oc_base + mi * 32 + (rg & 3) + ((rg >> 2) << 3) + half * 4;
                    out[(size_t)(nb * COUT + oc) * NPIX + hout * HW + pw] = acc[mi][nj][rg] + bv;
                }
            }
        }
    }
}

extern "C" void kernel_launch(void* const* d_in, const int* in_sizes, int n_in,
                              void* d_out, int out_size, void* d_ws, size_t ws_size,
                              hipStream_t stream) {
    const float* x    = (const float*)d_in[0];
    const float* Kw   = (const float*)d_in[1];
    const float* bias = (const float*)d_in[2];
    float* out = (float*)d_out;
    __bf16* W2 = (__bf16*)d_ws;   // needs 589824 bytes of workspace

    wt_transform_kernel<<<dim3(1152), dim3(256), 0, stream>>>(Kw, W2);
    conv_kernel<<<dim3(32 * 28, 2), dim3(256), 0, stream>>>(x, W2, bias, out);
}